// Round 18
// baseline (177.901 us; speedup 1.0000x reference)
//
#include <hip/hip_runtime.h>

#define N_USER 50000
#define N_ITEM 50000
#define N_EDGE 800000
#define D 128
#define NTOT   100000          // combined dst space: [0,50K)=items, [50K,100K)=users
#define NE2    1600000         // both directions' edges
#define BKT_SH 9               // 512 dsts per bucket
#define NBKT   196             // ceil(NTOT / 512)
#define CAP    12288           // LDS csr staging cap
#define SLOT   10240           // fixed per-bucket segment (mean 8192, sigma ~90)
#define QSTRIDE (50000 * 32)   // u16 elements per 32-dim quarter (3.2MB)

typedef __attribute__((ext_vector_type(8))) short     bf16x8;
typedef __attribute__((ext_vector_type(4))) float     f32x4;
typedef __attribute__((ext_vector_type(4))) unsigned short ushortx4;
typedef __attribute__((ext_vector_type(8))) unsigned short ushortx8;

__device__ __forceinline__ unsigned short f2bf(float f) {
    unsigned int u = __float_as_uint(f);
    unsigned int r = (u + 0x7fffu + ((u >> 16) & 1u)) >> 16;   // RNE
    return (unsigned short)r;
}
__device__ __forceinline__ float bf2f(unsigned short b) {
    return __uint_as_float(((unsigned int)b) << 16);
}

// ---------------------------------------------------------------------------
// SCATTER + PACK mega-kernel (1024 thr blocks). Pack writes QUARTER-MAJOR
// tables: T[q][node][32] (q = dim>>5), one quarter = 3.2MB (fits XCD L2).
// ---------------------------------------------------------------------------
#define SCAT_BLOCKS  196    // ceil(NE2 / 8192)
#define PACK_BLOCKS  3125   // 100000 rows * 32 lanes / 1024
#define PACKW_BLOCKS 8      // 8192 ids / 1024

__global__ __launch_bounds__(1024) void scatterpack_kernel(
    const float* __restrict__ user_emb, const int* __restrict__ user_ids,
    const float* __restrict__ item_x,
    const int* __restrict__ edge_ui, const int* __restrict__ edge_iu,
    const float* __restrict__ Wl_ui, const float* __restrict__ Wr_ui,
    const float* __restrict__ Wl_iu, const float* __restrict__ Wr_iu,
    unsigned short* T_user, unsigned short* T_item,
    unsigned short* WfragUI, unsigned short* WfragIU,
    int* __restrict__ bcur, unsigned int* __restrict__ records)
{
    const int b = blockIdx.x;
    const int tid = threadIdx.x;

    if (b < SCAT_BLOCKS) {
        __shared__ int bcnt[NBKT];
        __shared__ int bpos[NBKT];
        for (int i = tid; i < NBKT; i += 1024) bcnt[i] = 0;
        __syncthreads();

        const int e0 = b * 8192;
        unsigned int rec[8];
        int bkt[8], rnk[8];
#pragma unroll
        for (int j = 0; j < 8; ++j) {
            int e = e0 + j * 1024 + tid;
            bkt[j] = -1;
            if (e < NE2) {
                int s, d;
                if (e < N_EDGE) { s = edge_ui[e]; d = edge_ui[N_EDGE + e]; }
                else { int f = e - N_EDGE; s = edge_iu[f]; d = N_ITEM + edge_iu[N_EDGE + f]; }
                bkt[j] = d >> BKT_SH;
                rec[j] = (unsigned int)s | ((unsigned int)(d & 511) << 16);
                rnk[j] = atomicAdd(&bcnt[bkt[j]], 1);
            }
        }
        __syncthreads();
        for (int i = tid; i < NBKT; i += 1024) {
            int c = bcnt[i];
            bpos[i] = i * SLOT + (c ? atomicAdd(&bcur[i], c) : 0);
        }
        __syncthreads();
#pragma unroll
        for (int j = 0; j < 8; ++j) {
            if (bkt[j] >= 0) {
                int p = bpos[bkt[j]] + rnk[j];
                if (p < (bkt[j] + 1) * SLOT) records[p] = rec[j];   // slot-bound guard
            }
        }
    } else if (b < SCAT_BLOCKS + PACK_BLOCKS) {
        int gid = (b - SCAT_BLOCKS) * 1024 + tid;   // [0, 3.2M)
        int row = gid >> 5;                         // [0, 100000) exactly
        int c0 = (gid & 31) << 2;                   // dims c0..c0+3 (one quarter)
        const float* src;
        unsigned short* T;
        int trow;
        if (row < N_USER) { src = user_emb + (size_t)user_ids[row] * D; T = T_user; trow = row; }
        else              { src = item_x + (size_t)(row - N_USER) * D;  T = T_item; trow = row - N_USER; }
        const float4 v = *reinterpret_cast<const float4*>(src + c0);
        ushortx4 o;
        o.x = f2bf(v.x); o.y = f2bf(v.y); o.z = f2bf(v.z); o.w = f2bf(v.w);
        unsigned short* dst = T + (size_t)(c0 >> 5) * QSTRIDE + (size_t)trow * 32 + (c0 & 31);
        *reinterpret_cast<ushortx4*>(dst) = o;
    } else {
        int id = (b - SCAT_BLOCKS - PACK_BLOCKS) * 1024 + tid;   // [0, 8192)
        const float *Wl, *Wr;
        unsigned short* Wf;
        if (id < 4096) { Wl = Wl_ui; Wr = Wr_ui; Wf = WfragUI; }
        else { id -= 4096; Wl = Wl_iu; Wr = Wr_iu; Wf = WfragIU; }
        int lane = id & 63;
        int c    = (id >> 6) & 7;
        int ks   = id >> 9;
        int col  = c * 16 + (lane & 15);
        int k0   = ks * 32 + (lane >> 4) * 8;
        ushortx8 o;
#pragma unroll
        for (int i = 0; i < 8; ++i) {
            int k = k0 + i;
            float f = (k < D) ? Wl[(size_t)k * D + col] : Wr[(size_t)(k - D) * D + col];
            o[i] = f2bf(f);
        }
        *reinterpret_cast<ushortx8*>(Wf + (size_t)id * 8) = o;
    }
}

// ---------------------------------------------------------------------------
// Per-bucket CSR build in static slots: LDS counting-sort by dst within the
// bucket; emits offdeg[dst] = (global csr offset, degree) as uint2.
// ---------------------------------------------------------------------------
__global__ __launch_bounds__(1024) void csr_build_kernel(
    const unsigned int* __restrict__ records, const int* __restrict__ bcur,
    unsigned short* __restrict__ csr, uint2* __restrict__ offdeg)
{
    __shared__ int dcnt[512];
    __shared__ int sa[512], sb[512];
    __shared__ int dcur[512];
    __shared__ unsigned short stage[CAP];

    const int b    = blockIdx.x;
    const int tid  = threadIdx.x;
    const int base = b * SLOT;
    int nb = bcur[b];
    if (nb > SLOT) nb = SLOT;

    if (tid < 512) dcnt[tid] = 0;
    __syncthreads();

    for (int i = tid; i < nb; i += 1024)
        atomicAdd(&dcnt[records[base + i] >> 16], 1);
    __syncthreads();

    int* pa = sa; int* pb = sb;
    if (tid < 512) pa[tid] = dcnt[tid];
    __syncthreads();
    for (int d = 1; d < 512; d <<= 1) {
        if (tid < 512) pb[tid] = pa[tid] + ((tid >= d) ? pa[tid - d] : 0);
        __syncthreads();
        int* t = pa; pa = pb; pb = t;
    }
    if (tid < 512) {
        int excl = pa[tid] - dcnt[tid];
        dcur[tid] = excl;
        int dst = b * 512 + tid;
        if (dst < NTOT) offdeg[dst] = make_uint2((unsigned int)(base + excl),
                                                 (unsigned int)dcnt[tid]);
    }
    __syncthreads();

    if (nb <= CAP) {
        for (int i = tid; i < nb; i += 1024) {
            unsigned int r = records[base + i];
            int p = atomicAdd(&dcur[r >> 16], 1);
            stage[p] = (unsigned short)r;
        }
        __syncthreads();
        for (int i = tid; i < nb; i += 1024) csr[base + i] = stage[i];
    } else {
        for (int i = tid; i < nb; i += 1024) {
            unsigned int r = records[base + i];
            int p = atomicAdd(&dcur[r >> 16], 1);
            csr[base + p] = (unsigned short)r;
        }
    }
}

// ---------------------------------------------------------------------------
// Aggregate (mean), XCD-QUARTERED: block class = blockIdx&7 = (side, quarter)
// -> pinned XCD (empirical %8 round-robin; perf-only); per-class working set
// = one 3.2MB quarter table, L2-resident.
// Wave = one row-visit (row, quarter): eo=lane>>4 edge slot, dl=lane&15
// dim-pair -> one gather instruction = 4 edges x 64B = 256B. csr via
// lane-cooperative chunk + __shfl. 32-edge double-chunk = 8 loads in flight.
// Merge across edge slots via 2x shfl_xor; eo==0 lanes write 4B each.
// ---------------------------------------------------------------------------
__global__ __launch_bounds__(256) void agg5_kernel(
    const unsigned short* __restrict__ T_user, const unsigned short* __restrict__ T_item,
    const uint2* __restrict__ offdeg, const unsigned short* __restrict__ csr,
    unsigned short* __restrict__ dout_u16)
{
    const int b    = blockIdx.x;            // [0, 100000)
    const int cls  = b & 7;                 // -> XCD
    const int side = cls >> 2;              // 0: item dst (gathers user), 1: user dst
    const int q    = cls & 3;               // dim quarter
    const int rg   = b >> 3;                // [0, 12500)
    const int wave = threadIdx.x >> 6;
    const int lane = threadIdx.x & 63;
    const int eo   = lane >> 4;             // edge slot 0..3
    const int dl   = lane & 15;             // dim-pair 0..15

    const int r = rg * 4 + wave;            // side-local row [0, 50000)
    const unsigned short* Tg = (side ? T_item : T_user) + (size_t)q * QSTRIDE;
    const int dr = side ? (N_ITEM + r) : r;
    unsigned short* outp = side ? (dout_u16 + (size_t)r * 256)
                                : (dout_u16 + (size_t)(N_USER + r) * 256);

    const uint2 od = offdeg[dr];
    const int o0 = (int)od.x;
    const int deg = (int)od.y;
    const int o1 = o0 + deg;
    const int doff = dl * 2;                // u16 offset of dim-pair in quarter
    float ax = 0.f, ay = 0.f;
    int i = o0;

    // 32-edge double-chunk: 8 gathers in flight
    for (; i + 31 < o1; i += 32) {
        int cv0 = csr[i + dl];
        int cv1 = csr[i + 16 + dl];
        unsigned int w[8];
#pragma unroll
        for (int g = 0; g < 4; ++g) {
            int s = __shfl(cv0, g * 4 + eo);
            w[g] = *reinterpret_cast<const unsigned int*>(Tg + (size_t)s * 32 + doff);
        }
#pragma unroll
        for (int g = 0; g < 4; ++g) {
            int s = __shfl(cv1, g * 4 + eo);
            w[4 + g] = *reinterpret_cast<const unsigned int*>(Tg + (size_t)s * 32 + doff);
        }
#pragma unroll
        for (int g = 0; g < 8; ++g) {
            ax += bf2f((unsigned short)w[g]);
            ay += bf2f((unsigned short)(w[g] >> 16));
        }
    }
    // 16-edge chunk
    if (i + 15 < o1) {
        int cv = csr[i + dl];
        unsigned int w[4];
#pragma unroll
        for (int g = 0; g < 4; ++g) {
            int s = __shfl(cv, g * 4 + eo);
            w[g] = *reinterpret_cast<const unsigned int*>(Tg + (size_t)s * 32 + doff);
        }
#pragma unroll
        for (int g = 0; g < 4; ++g) {
            ax += bf2f((unsigned short)w[g]);
            ay += bf2f((unsigned short)(w[g] >> 16));
        }
        i += 16;
    }
    // tail (<16): loads unconditional into padded-safe region, adds predicated
    int rem = o1 - i;
    if (rem > 0) {
        int cv = csr[i + dl];
#pragma unroll
        for (int g = 0; g < 4; ++g) {
            if (g * 4 < rem) {
                int s = __shfl(cv, g * 4 + eo);
                unsigned int w = *reinterpret_cast<const unsigned int*>(Tg + (size_t)s * 32 + doff);
                if (g * 4 + eo < rem) {
                    ax += bf2f((unsigned short)w);
                    ay += bf2f((unsigned short)(w >> 16));
                }
            }
        }
    }

    // merge the 4 edge slots (lanes dl, dl+16, dl+32, dl+48 share dims)
    ax += __shfl_xor(ax, 16); ay += __shfl_xor(ay, 16);
    ax += __shfl_xor(ax, 32); ay += __shfl_xor(ay, 32);

    float sc = (deg > 0) ? 1.0f / (float)deg : 0.0f;
    if (eo == 0) {
        unsigned int outw = (unsigned int)f2bf(ax * sc) | ((unsigned int)f2bf(ay * sc) << 16);
        *reinterpret_cast<unsigned int*>(outp + q * 32 + doff) = outw;
    }
}

// ---------------------------------------------------------------------------
// MFMA finish, head from d_out (stride 256, in-place row-aliased), tail from
// QUARTER-MAJOR self table: dims (ks-4)*32 + kg*8 live at quarter (ks-4),
// in-quarter offset arow*32 + kg*8 (16B contiguous).
// ---------------------------------------------------------------------------
#define NB_FIN 782   // ceil(50000/64)

__global__ __launch_bounds__(256) void finish2c_kernel(
    unsigned short* dout_u16,
    const unsigned short* __restrict__ T_user, const unsigned short* __restrict__ T_item,
    const unsigned short* __restrict__ WfragUI, const unsigned short* __restrict__ WfragIU,
    const float* __restrict__ b_ui, const float* __restrict__ b_iu)
{
    const int b = blockIdx.x;
    const unsigned short *headBase, *Ts, *Wfrag;
    const float* bias;
    float* outp;
    int rowBase;
    if (b < NB_FIN) {
        headBase = dout_u16 + (size_t)N_USER * 256;
        Ts = T_item; Wfrag = WfragUI; bias = b_ui;
        outp = reinterpret_cast<float*>(dout_u16) + (size_t)N_USER * 128;
        rowBase = b * 64;
    } else {
        headBase = dout_u16;
        Ts = T_user; Wfrag = WfragIU; bias = b_iu;
        outp = reinterpret_cast<float*>(dout_u16);
        rowBase = (b - NB_FIN) * 64;
    }

    const int tid  = threadIdx.x;
    const int wave = tid >> 6;
    const int lane = tid & 63;
    const int kg   = lane >> 4;
    rowBase += wave * 16;

    int arow = rowBase + (lane & 15);
    int arow_c = (arow < 50000) ? arow : 49999;
    const unsigned short* head_ptr = headBase + (size_t)arow_c * 256 + kg * 8;

    f32x4 acc[8];
#pragma unroll
    for (int c = 0; c < 8; ++c) acc[c] = (f32x4){0.f, 0.f, 0.f, 0.f};

#pragma unroll
    for (int ks = 0; ks < 8; ++ks) {
        bf16x8 a;
        if (ks < 4) {
            a = *reinterpret_cast<const bf16x8*>(head_ptr + ks * 32);       // agg (Wl)
        } else {
            a = *reinterpret_cast<const bf16x8*>(                           // self (Wr)
                Ts + (size_t)(ks - 4) * QSTRIDE + (size_t)arow_c * 32 + kg * 8);
        }
        const unsigned short* bptr = Wfrag + ((size_t)(ks * 8) * 64 + lane) * 8;
#pragma unroll
        for (int c = 0; c < 8; ++c) {
            bf16x8 bb = *reinterpret_cast<const bf16x8*>(bptr + (size_t)c * 512);
            acc[c] = __builtin_amdgcn_mfma_f32_16x16x32_bf16(a, bb, acc[c], 0, 0, 0);
        }
    }

    const int orow0 = rowBase + kg * 4;
    const int ocol  = lane & 15;
#pragma unroll
    for (int c = 0; c < 8; ++c) {
        float bv = bias[c * 16 + ocol];
#pragma unroll
        for (int r = 0; r < 4; ++r) {
            int row = orow0 + r;
            if (row < 50000) outp[(size_t)row * 128 + c * 16 + ocol] = acc[c][r] + bv;
        }
    }
}

// ---------------------------------------------------------------------------
extern "C" void kernel_launch(void* const* d_in, const int* in_sizes, int n_in,
                              void* d_out, int out_size, void* d_ws, size_t ws_size,
                              hipStream_t stream) {
    const int*   user_ids = (const int*)d_in[0];
    const float* item_x   = (const float*)d_in[1];
    const int*   edge_ui  = (const int*)d_in[2];
    const int*   edge_iu  = (const int*)d_in[3];
    const float* user_emb = (const float*)d_in[4];
    const float* W_l_ui   = (const float*)d_in[5];
    const float* W_r_ui   = (const float*)d_in[6];
    const float* b_ui     = (const float*)d_in[7];
    const float* W_l_iu   = (const float*)d_in[8];
    const float* W_r_iu   = (const float*)d_in[9];
    const float* b_iu     = (const float*)d_in[10];

    unsigned short* dout_u16 = (unsigned short*)d_out;

    // Workspace (16B-aligned blocks first)
    unsigned short* WfragUI = (unsigned short*)d_ws;            // 32768 u16
    unsigned short* WfragIU = WfragUI + 32768;                  // 32768 u16
    unsigned short* T_user  = WfragIU + 32768;                  // 4 quarters (12.8MB)
    unsigned short* T_item  = T_user + (size_t)4 * QSTRIDE;     // 12.8MB
    unsigned int*   records = (unsigned int*)(T_item + (size_t)4 * QSTRIDE);   // NBKT*SLOT (8.0MB)
    unsigned short* csr     = (unsigned short*)(records + (size_t)NBKT * SLOT); // NBKT*SLOT+16 (4.0MB)
    uint2* offdeg = (uint2*)(csr + (size_t)NBKT * SLOT + 16);   // NTOT (800KB)
    int*   bcur   = (int*)(offdeg + NTOT);                      // NBKT

    hipMemsetAsync(bcur, 0, NBKT * sizeof(int), stream);

    scatterpack_kernel<<<SCAT_BLOCKS + PACK_BLOCKS + PACKW_BLOCKS, 1024, 0, stream>>>(
        user_emb, user_ids, item_x, edge_ui, edge_iu,
        W_l_ui, W_r_ui, W_l_iu, W_r_iu,
        T_user, T_item, WfragUI, WfragIU, bcur, records);
    csr_build_kernel<<<NBKT, 1024, 0, stream>>>(records, bcur, csr, offdeg);
    agg5_kernel<<<100000, 256, 0, stream>>>(T_user, T_item, offdeg, csr, dout_u16);
    finish2c_kernel<<<2 * NB_FIN, 256, 0, stream>>>(
        dout_u16, T_user, T_item, WfragUI, WfragIU, b_ui, b_iu);
}

// Round 19
// 124.570 us; speedup vs baseline: 1.4281x; 1.4281x over previous
//
#include <hip/hip_runtime.h>

#define N_USER 50000
#define N_ITEM 50000
#define N_EDGE 800000
#define D 128
#define NTOT   100000          // combined dst space: [0,50K)=items, [50K,100K)=users
#define NE2    1600000         // both directions' edges
#define BKT_SH 9               // 512 dsts per bucket
#define NBKT   196             // ceil(NTOT / 512)
#define CAP    12288           // LDS csr staging cap
#define SLOT   10240           // fixed per-bucket segment (mean 8192, sigma ~90)

typedef __attribute__((ext_vector_type(8))) short     bf16x8;
typedef __attribute__((ext_vector_type(4))) float     f32x4;
typedef __attribute__((ext_vector_type(4))) unsigned short ushortx4;
typedef __attribute__((ext_vector_type(8))) unsigned short ushortx8;

__device__ __forceinline__ unsigned short f2bf(float f) {
    unsigned int u = __float_as_uint(f);
    unsigned int r = (u + 0x7fffu + ((u >> 16) & 1u)) >> 16;   // RNE
    return (unsigned short)r;
}
__device__ __forceinline__ float bf2f(unsigned short b) {
    return __uint_as_float(((unsigned int)b) << 16);
}

// ---------------------------------------------------------------------------
// SCATTER + PACK mega-kernel (1024 thr blocks).
//  [0, 196)        scatter: records into STATIC bucket slots
//  [196, 3321)     pack features -> compact bf16 tables (row-major, stride 128)
//  [3321, 3329)    pack W frags
// Record = src16 | dstlow9<<16.
// ---------------------------------------------------------------------------
#define SCAT_BLOCKS  196    // ceil(NE2 / 8192)
#define PACK_BLOCKS  3125   // 100000 rows * 32 lanes / 1024
#define PACKW_BLOCKS 8      // 8192 ids / 1024

__global__ __launch_bounds__(1024) void scatterpack_kernel(
    const float* __restrict__ user_emb, const int* __restrict__ user_ids,
    const float* __restrict__ item_x,
    const int* __restrict__ edge_ui, const int* __restrict__ edge_iu,
    const float* __restrict__ Wl_ui, const float* __restrict__ Wr_ui,
    const float* __restrict__ Wl_iu, const float* __restrict__ Wr_iu,
    unsigned short* T_user, unsigned short* T_item,
    unsigned short* WfragUI, unsigned short* WfragIU,
    int* __restrict__ bcur, unsigned int* __restrict__ records)
{
    const int b = blockIdx.x;
    const int tid = threadIdx.x;

    if (b < SCAT_BLOCKS) {
        __shared__ int bcnt[NBKT];
        __shared__ int bpos[NBKT];
        for (int i = tid; i < NBKT; i += 1024) bcnt[i] = 0;
        __syncthreads();

        const int e0 = b * 8192;
        unsigned int rec[8];
        int bkt[8], rnk[8];
#pragma unroll
        for (int j = 0; j < 8; ++j) {
            int e = e0 + j * 1024 + tid;
            bkt[j] = -1;
            if (e < NE2) {
                int s, d;
                if (e < N_EDGE) { s = edge_ui[e]; d = edge_ui[N_EDGE + e]; }
                else { int f = e - N_EDGE; s = edge_iu[f]; d = N_ITEM + edge_iu[N_EDGE + f]; }
                bkt[j] = d >> BKT_SH;
                rec[j] = (unsigned int)s | ((unsigned int)(d & 511) << 16);
                rnk[j] = atomicAdd(&bcnt[bkt[j]], 1);
            }
        }
        __syncthreads();
        for (int i = tid; i < NBKT; i += 1024) {
            int c = bcnt[i];
            bpos[i] = i * SLOT + (c ? atomicAdd(&bcur[i], c) : 0);
        }
        __syncthreads();
#pragma unroll
        for (int j = 0; j < 8; ++j) {
            if (bkt[j] >= 0) {
                int p = bpos[bkt[j]] + rnk[j];
                if (p < (bkt[j] + 1) * SLOT) records[p] = rec[j];   // slot-bound guard
            }
        }
    } else if (b < SCAT_BLOCKS + PACK_BLOCKS) {
        int gid = (b - SCAT_BLOCKS) * 1024 + tid;   // [0, 3.2M)
        int row = gid >> 5;                         // [0, 100000) exactly
        int c = (gid & 31) << 2;
        const float* src;
        unsigned short* dst;
        if (row < N_USER) {
            src = user_emb + (size_t)user_ids[row] * D;
            dst = T_user + (size_t)row * 128;
        } else {
            int r = row - N_USER;
            src = item_x + (size_t)r * D;
            dst = T_item + (size_t)r * 128;
        }
        const float4 v = *reinterpret_cast<const float4*>(src + c);
        ushortx4 o;
        o.x = f2bf(v.x); o.y = f2bf(v.y); o.z = f2bf(v.z); o.w = f2bf(v.w);
        *reinterpret_cast<ushortx4*>(dst + c) = o;
    } else {
        int id = (b - SCAT_BLOCKS - PACK_BLOCKS) * 1024 + tid;   // [0, 8192)
        const float *Wl, *Wr;
        unsigned short* Wf;
        if (id < 4096) { Wl = Wl_ui; Wr = Wr_ui; Wf = WfragUI; }
        else { id -= 4096; Wl = Wl_iu; Wr = Wr_iu; Wf = WfragIU; }
        int lane = id & 63;
        int c    = (id >> 6) & 7;
        int ks   = id >> 9;
        int col  = c * 16 + (lane & 15);
        int k0   = ks * 32 + (lane >> 4) * 8;
        ushortx8 o;
#pragma unroll
        for (int i = 0; i < 8; ++i) {
            int k = k0 + i;
            float f = (k < D) ? Wl[(size_t)k * D + col] : Wr[(size_t)(k - D) * D + col];
            o[i] = f2bf(f);
        }
        *reinterpret_cast<ushortx8*>(Wf + (size_t)id * 8) = o;
    }
}

// ---------------------------------------------------------------------------
// Per-bucket CSR build in static slots: LDS counting-sort by dst within the
// bucket; emits offdeg[dst] = (global csr offset, degree) as uint2.
// ---------------------------------------------------------------------------
__global__ __launch_bounds__(1024) void csr_build_kernel(
    const unsigned int* __restrict__ records, const int* __restrict__ bcur,
    unsigned short* __restrict__ csr, uint2* __restrict__ offdeg)
{
    __shared__ int dcnt[512];
    __shared__ int sa[512], sb[512];
    __shared__ int dcur[512];
    __shared__ unsigned short stage[CAP];

    const int b    = blockIdx.x;
    const int tid  = threadIdx.x;
    const int base = b * SLOT;
    int nb = bcur[b];
    if (nb > SLOT) nb = SLOT;

    if (tid < 512) dcnt[tid] = 0;
    __syncthreads();

    for (int i = tid; i < nb; i += 1024)
        atomicAdd(&dcnt[records[base + i] >> 16], 1);
    __syncthreads();

    int* pa = sa; int* pb = sb;
    if (tid < 512) pa[tid] = dcnt[tid];
    __syncthreads();
    for (int d = 1; d < 512; d <<= 1) {
        if (tid < 512) pb[tid] = pa[tid] + ((tid >= d) ? pa[tid - d] : 0);
        __syncthreads();
        int* t = pa; pa = pb; pb = t;
    }
    if (tid < 512) {
        int excl = pa[tid] - dcnt[tid];
        dcur[tid] = excl;
        int dst = b * 512 + tid;
        if (dst < NTOT) offdeg[dst] = make_uint2((unsigned int)(base + excl),
                                                 (unsigned int)dcnt[tid]);
    }
    __syncthreads();

    if (nb <= CAP) {
        for (int i = tid; i < nb; i += 1024) {
            unsigned int r = records[base + i];
            int p = atomicAdd(&dcur[r >> 16], 1);
            stage[p] = (unsigned short)r;
        }
        __syncthreads();
        for (int i = tid; i < nb; i += 1024) csr[base + i] = stage[i];
    } else {
        for (int i = tid; i < nb; i += 1024) {
            unsigned int r = records[base + i];
            int p = atomicAdd(&dcur[r >> 16], 1);
            csr[base + p] = (unsigned short)r;
        }
    }
}

// ---------------------------------------------------------------------------
// Aggregate (mean), CHUNK+READLANE with PREFETCH + FLAT TAIL:
// 256 thr = 4 free-running waves, one wave per dst row, lane owns dims
// [2l, 2l+1]. csr chunk k+1 prefetched while chunk k's 16 gathers are in
// flight; tail is ONE 15-wide clamped level (duplicate loads hit the same
// cacheline; adds predicated) so all tail gathers issue in a single burst.
// csr is padded by 32 entries so prefetch never faults.
// ---------------------------------------------------------------------------
__global__ __launch_bounds__(256) void agg2c_kernel(
    const unsigned short* __restrict__ T_user, const unsigned short* __restrict__ T_item,
    const uint2* __restrict__ offdeg, const unsigned short* __restrict__ csr,
    unsigned short* __restrict__ dout_u16)
{
    int r = (blockIdx.x * blockDim.x + threadIdx.x) >> 6;
    if (r >= NTOT) return;
    const int lane = threadIdx.x & 63;
    const int dl = lane & 15;
    const unsigned short* Tg;
    unsigned short* outp;
    if (r < N_ITEM) { Tg = T_user; outp = dout_u16 + (size_t)(N_USER + r) * 256; }
    else            { Tg = T_item; outp = dout_u16 + (size_t)(r - N_ITEM) * 256; }

    const uint2 od = offdeg[r];
    const int o0 = (int)od.x;
    const int deg = (int)od.y;
    const int o1 = o0 + deg;
    const int co = lane * 2;
    float ax = 0.f, ay = 0.f;
    int i = o0;

    // first chunk load (pad-safe even for deg==0)
    int cv = csr[i + dl];

    // main: 16 edges per chunk; next chunk prefetched before this chunk's
    // gathers so its latency hides under them. Srcs distributed via readlane
    // (SGPR-based gather addressing).
    for (; i + 15 < o1; i += 16) {
        int cvc = cv;
        cv = csr[i + 16 + dl];          // prefetch (csr padded by 32)
        unsigned int w[16];
#pragma unroll
        for (int p = 0; p < 16; ++p) {
            int s = __builtin_amdgcn_readlane(cvc, p);
            w[p] = *reinterpret_cast<const unsigned int*>(Tg + (size_t)s * 128 + co);
        }
#pragma unroll
        for (int p = 0; p < 16; ++p) {
            ax += bf2f((unsigned short)w[p]);
            ay += bf2f((unsigned short)(w[p] >> 16));
        }
    }

    // tail: rem in [1,15]; cv already holds the chunk at i.
    // One flat 15-wide level: index clamped to rem-1 (duplicates = same
    // cacheline, near-free), adds predicated on p < rem.
    int rem = o1 - i;
    if (rem > 0) {
        unsigned int w[15];
        int last = rem - 1;
#pragma unroll
        for (int p = 0; p < 15; ++p) {
            int idx = (p < last) ? p : last;
            int s = __builtin_amdgcn_readlane(cv, idx);
            w[p] = *reinterpret_cast<const unsigned int*>(Tg + (size_t)s * 128 + co);
        }
#pragma unroll
        for (int p = 0; p < 15; ++p) {
            if (p < rem) {
                ax += bf2f((unsigned short)w[p]);
                ay += bf2f((unsigned short)(w[p] >> 16));
            }
        }
    }

    float sc = (deg > 0) ? 1.0f / (float)deg : 0.0f;
    unsigned int outw = (unsigned int)f2bf(ax * sc) | ((unsigned int)f2bf(ay * sc) << 16);
    *reinterpret_cast<unsigned int*>(outp + co) = outw;
}

// ---------------------------------------------------------------------------
// MFMA finish (round-6 structure), head from d_out (stride 256, in-place
// row-aliased: bf16[r][256] == fp32[r][128] bytes; wave stores depend on all
// its loads; waves own disjoint rows), tail from compact self table Ts.
// ---------------------------------------------------------------------------
#define NB_FIN 782   // ceil(50000/64)

__global__ __launch_bounds__(256) void finish2c_kernel(
    unsigned short* dout_u16,
    const unsigned short* __restrict__ T_user, const unsigned short* __restrict__ T_item,
    const unsigned short* __restrict__ WfragUI, const unsigned short* __restrict__ WfragIU,
    const float* __restrict__ b_ui, const float* __restrict__ b_iu)
{
    const int b = blockIdx.x;
    const unsigned short *headBase, *Ts, *Wfrag;
    const float* bias;
    float* outp;
    int rowBase;
    if (b < NB_FIN) {
        headBase = dout_u16 + (size_t)N_USER * 256;
        Ts = T_item; Wfrag = WfragUI; bias = b_ui;
        outp = reinterpret_cast<float*>(dout_u16) + (size_t)N_USER * 128;
        rowBase = b * 64;
    } else {
        headBase = dout_u16;
        Ts = T_user; Wfrag = WfragIU; bias = b_iu;
        outp = reinterpret_cast<float*>(dout_u16);
        rowBase = (b - NB_FIN) * 64;
    }

    const int tid  = threadIdx.x;
    const int wave = tid >> 6;
    const int lane = tid & 63;
    const int kg   = lane >> 4;
    rowBase += wave * 16;

    int arow = rowBase + (lane & 15);
    int arow_c = (arow < 50000) ? arow : 49999;
    const unsigned short* head_ptr = headBase + (size_t)arow_c * 256 + kg * 8;
    const unsigned short* tail_ptr = Ts + (size_t)arow_c * 128 + kg * 8;

    f32x4 acc[8];
#pragma unroll
    for (int c = 0; c < 8; ++c) acc[c] = (f32x4){0.f, 0.f, 0.f, 0.f};

#pragma unroll
    for (int ks = 0; ks < 8; ++ks) {
        bf16x8 a;
        if (ks < 4) a = *reinterpret_cast<const bf16x8*>(head_ptr + ks * 32);       // agg (Wl)
        else        a = *reinterpret_cast<const bf16x8*>(tail_ptr + (ks - 4) * 32); // self (Wr)
        const unsigned short* bptr = Wfrag + ((size_t)(ks * 8) * 64 + lane) * 8;
#pragma unroll
        for (int c = 0; c < 8; ++c) {
            bf16x8 bb = *reinterpret_cast<const bf16x8*>(bptr + (size_t)c * 512);
            acc[c] = __builtin_amdgcn_mfma_f32_16x16x32_bf16(a, bb, acc[c], 0, 0, 0);
        }
    }

    const int orow0 = rowBase + kg * 4;
    const int ocol  = lane & 15;
#pragma unroll
    for (int c = 0; c < 8; ++c) {
        float bv = bias[c * 16 + ocol];
#pragma unroll
        for (int r = 0; r < 4; ++r) {
            int row = orow0 + r;
            if (row < 50000) outp[(size_t)row * 128 + c * 16 + ocol] = acc[c][r] + bv;
        }
    }
}

// ---------------------------------------------------------------------------
extern "C" void kernel_launch(void* const* d_in, const int* in_sizes, int n_in,
                              void* d_out, int out_size, void* d_ws, size_t ws_size,
                              hipStream_t stream) {
    const int*   user_ids = (const int*)d_in[0];
    const float* item_x   = (const float*)d_in[1];
    const int*   edge_ui  = (const int*)d_in[2];
    const int*   edge_iu  = (const int*)d_in[3];
    const float* user_emb = (const float*)d_in[4];
    const float* W_l_ui   = (const float*)d_in[5];
    const float* W_r_ui   = (const float*)d_in[6];
    const float* b_ui     = (const float*)d_in[7];
    const float* W_l_iu   = (const float*)d_in[8];
    const float* W_r_iu   = (const float*)d_in[9];
    const float* b_iu     = (const float*)d_in[10];

    unsigned short* dout_u16 = (unsigned short*)d_out;

    // Workspace (16B-aligned blocks first)
    unsigned short* WfragUI = (unsigned short*)d_ws;            // 32768 u16
    unsigned short* WfragIU = WfragUI + 32768;                  // 32768 u16
    unsigned short* T_user  = WfragIU + 32768;                  // 12.8MB
    unsigned short* T_item  = T_user + (size_t)N_USER * 128;    // 12.8MB
    unsigned int*   records = (unsigned int*)(T_item + (size_t)N_ITEM * 128);  // NBKT*SLOT (8.0MB)
    unsigned short* csr     = (unsigned short*)(records + (size_t)NBKT * SLOT); // NBKT*SLOT+32 (4.0MB)
    uint2* offdeg = (uint2*)(csr + (size_t)NBKT * SLOT + 32);   // NTOT (800KB)
    int*   bcur   = (int*)(offdeg + NTOT);                      // NBKT

    hipMemsetAsync(bcur, 0, NBKT * sizeof(int), stream);

    scatterpack_kernel<<<SCAT_BLOCKS + PACK_BLOCKS + PACKW_BLOCKS, 1024, 0, stream>>>(
        user_emb, user_ids, item_x, edge_ui, edge_iu,
        W_l_ui, W_r_ui, W_l_iu, W_r_iu,
        T_user, T_item, WfragUI, WfragIU, bcur, records);
    csr_build_kernel<<<NBKT, 1024, 0, stream>>>(records, bcur, csr, offdeg);
    agg2c_kernel<<<(NTOT * 64) / 256, 256, 0, stream>>>(T_user, T_item, offdeg, csr, dout_u16);
    finish2c_kernel<<<2 * NB_FIN, 256, 0, stream>>>(
        dout_u16, T_user, T_item, WfragUI, WfragIU, b_ui, b_iu);
}

// Round 20
// 121.556 us; speedup vs baseline: 1.4635x; 1.0248x over previous
//
#include <hip/hip_runtime.h>

#define N_USER 50000
#define N_ITEM 50000
#define N_EDGE 800000
#define D 128
#define NTOT   100000          // combined dst space: [0,50K)=items, [50K,100K)=users
#define NE2    1600000         // both directions' edges
#define BKT_SH 9               // 512 dsts per bucket
#define NBKT   196             // ceil(NTOT / 512)
#define CAP    12288           // LDS csr staging cap
#define SLOT   10240           // fixed per-bucket segment (mean 8192, sigma ~90 -> 22 sigma slack)

typedef __attribute__((ext_vector_type(8))) short     bf16x8;
typedef __attribute__((ext_vector_type(4))) float     f32x4;
typedef __attribute__((ext_vector_type(4))) unsigned short ushortx4;
typedef __attribute__((ext_vector_type(8))) unsigned short ushortx8;

__device__ __forceinline__ unsigned short f2bf(float f) {
    unsigned int u = __float_as_uint(f);
    unsigned int r = (u + 0x7fffu + ((u >> 16) & 1u)) >> 16;   // RNE
    return (unsigned short)r;
}
__device__ __forceinline__ float bf2f(unsigned short b) {
    return __uint_as_float(((unsigned int)b) << 16);
}

// ---------------------------------------------------------------------------
// SCATTER + PACK mega-kernel (1024 thr blocks).
//  [0, 196)        scatter: records into STATIC bucket slots (base = bkt*SLOT,
//                  relative cursor in bcur[], rank-captured, atomic-free store)
//  [196, 3321)     pack features -> compact bf16 tables (32 rows/block)
//  [3321, 3329)    pack W frags (2 x 4096 ids)
// Record = src16 | dstlow9<<16. Scatter blocks first so they start while the
// pack blocks keep the machine busy (mutual latency hiding).
// ---------------------------------------------------------------------------
#define SCAT_BLOCKS  196    // ceil(NE2 / 8192)
#define PACK_BLOCKS  3125   // 100000 rows * 32 lanes / 1024
#define PACKW_BLOCKS 8      // 8192 ids / 1024

__global__ __launch_bounds__(1024) void scatterpack_kernel(
    const float* __restrict__ user_emb, const int* __restrict__ user_ids,
    const float* __restrict__ item_x,
    const int* __restrict__ edge_ui, const int* __restrict__ edge_iu,
    const float* __restrict__ Wl_ui, const float* __restrict__ Wr_ui,
    const float* __restrict__ Wl_iu, const float* __restrict__ Wr_iu,
    unsigned short* T_user, unsigned short* T_item,
    unsigned short* WfragUI, unsigned short* WfragIU,
    int* __restrict__ bcur, unsigned int* __restrict__ records)
{
    const int b = blockIdx.x;
    const int tid = threadIdx.x;

    if (b < SCAT_BLOCKS) {
        __shared__ int bcnt[NBKT];
        __shared__ int bpos[NBKT];
        for (int i = tid; i < NBKT; i += 1024) bcnt[i] = 0;
        __syncthreads();

        const int e0 = b * 8192;
        unsigned int rec[8];
        int bkt[8], rnk[8];
#pragma unroll
        for (int j = 0; j < 8; ++j) {
            int e = e0 + j * 1024 + tid;
            bkt[j] = -1;
            if (e < NE2) {
                int s, d;
                if (e < N_EDGE) { s = edge_ui[e]; d = edge_ui[N_EDGE + e]; }
                else { int f = e - N_EDGE; s = edge_iu[f]; d = N_ITEM + edge_iu[N_EDGE + f]; }
                bkt[j] = d >> BKT_SH;
                rec[j] = (unsigned int)s | ((unsigned int)(d & 511) << 16);
                rnk[j] = atomicAdd(&bcnt[bkt[j]], 1);
            }
        }
        __syncthreads();
        for (int i = tid; i < NBKT; i += 1024) {
            int c = bcnt[i];
            bpos[i] = i * SLOT + (c ? atomicAdd(&bcur[i], c) : 0);
        }
        __syncthreads();
#pragma unroll
        for (int j = 0; j < 8; ++j) {
            if (bkt[j] >= 0) {
                int p = bpos[bkt[j]] + rnk[j];
                if (p < (bkt[j] + 1) * SLOT) records[p] = rec[j];   // slot-bound guard
            }
        }
    } else if (b < SCAT_BLOCKS + PACK_BLOCKS) {
        int gid = (b - SCAT_BLOCKS) * 1024 + tid;   // [0, 3.2M)
        int row = gid >> 5;                         // [0, 100000) exactly
        int c = (gid & 31) << 2;
        const float* src;
        unsigned short* dst;
        if (row < N_USER) {
            src = user_emb + (size_t)user_ids[row] * D;
            dst = T_user + (size_t)row * 128;
        } else {
            int r = row - N_USER;
            src = item_x + (size_t)r * D;
            dst = T_item + (size_t)r * 128;
        }
        const float4 v = *reinterpret_cast<const float4*>(src + c);
        ushortx4 o;
        o.x = f2bf(v.x); o.y = f2bf(v.y); o.z = f2bf(v.z); o.w = f2bf(v.w);
        *reinterpret_cast<ushortx4*>(dst + c) = o;
    } else {
        int id = (b - SCAT_BLOCKS - PACK_BLOCKS) * 1024 + tid;   // [0, 8192)
        const float *Wl, *Wr;
        unsigned short* Wf;
        if (id < 4096) { Wl = Wl_ui; Wr = Wr_ui; Wf = WfragUI; }
        else { id -= 4096; Wl = Wl_iu; Wr = Wr_iu; Wf = WfragIU; }
        int lane = id & 63;
        int c    = (id >> 6) & 7;
        int ks   = id >> 9;
        int col  = c * 16 + (lane & 15);
        int k0   = ks * 32 + (lane >> 4) * 8;
        ushortx8 o;
#pragma unroll
        for (int i = 0; i < 8; ++i) {
            int k = k0 + i;
            float f = (k < D) ? Wl[(size_t)k * D + col] : Wr[(size_t)(k - D) * D + col];
            o[i] = f2bf(f);
        }
        *reinterpret_cast<ushortx8*>(Wf + (size_t)id * 8) = o;
    }
}

// ---------------------------------------------------------------------------
// Per-bucket CSR build in static slots: LDS counting-sort by dst within the
// bucket; emits offdeg[dst] = (global csr offset, degree) as uint2.
// ---------------------------------------------------------------------------
__global__ __launch_bounds__(1024) void csr_build_kernel(
    const unsigned int* __restrict__ records, const int* __restrict__ bcur,
    unsigned short* __restrict__ csr, uint2* __restrict__ offdeg)
{
    __shared__ int dcnt[512];
    __shared__ int sa[512], sb[512];
    __shared__ int dcur[512];
    __shared__ unsigned short stage[CAP];

    const int b    = blockIdx.x;
    const int tid  = threadIdx.x;
    const int base = b * SLOT;
    int nb = bcur[b];
    if (nb > SLOT) nb = SLOT;

    if (tid < 512) dcnt[tid] = 0;
    __syncthreads();

    for (int i = tid; i < nb; i += 1024)
        atomicAdd(&dcnt[records[base + i] >> 16], 1);
    __syncthreads();

    int* pa = sa; int* pb = sb;
    if (tid < 512) pa[tid] = dcnt[tid];
    __syncthreads();
    for (int d = 1; d < 512; d <<= 1) {
        if (tid < 512) pb[tid] = pa[tid] + ((tid >= d) ? pa[tid - d] : 0);
        __syncthreads();
        int* t = pa; pa = pb; pb = t;
    }
    if (tid < 512) {
        int excl = pa[tid] - dcnt[tid];
        dcur[tid] = excl;
        int dst = b * 512 + tid;
        if (dst < NTOT) offdeg[dst] = make_uint2((unsigned int)(base + excl),
                                                 (unsigned int)dcnt[tid]);
    }
    __syncthreads();

    if (nb <= CAP) {
        for (int i = tid; i < nb; i += 1024) {
            unsigned int r = records[base + i];
            int p = atomicAdd(&dcur[r >> 16], 1);
            stage[p] = (unsigned short)r;
        }
        __syncthreads();
        for (int i = tid; i < nb; i += 1024) csr[base + i] = stage[i];
    } else {
        for (int i = tid; i < nb; i += 1024) {
            unsigned int r = records[base + i];
            int p = atomicAdd(&dcur[r >> 16], 1);
            csr[base + p] = (unsigned short)r;
        }
    }
}

// ---------------------------------------------------------------------------
// Aggregate (mean), CHUNK+READLANE gather: 256 thr = 4 free-running waves,
// one wave per dst row, lane owns dims [2l,2l+1].
// csr indices from ONE lane-cooperative 32B chunk load distributed via
// v_readlane -> SGPR src -> scalar-based gather addressing; 16 in flight.
// Per-dst extent from offdeg (uint2). Writes bf16 mean into d_out heads.
// ---------------------------------------------------------------------------
__global__ __launch_bounds__(256) void agg2c_kernel(
    const unsigned short* __restrict__ T_user, const unsigned short* __restrict__ T_item,
    const uint2* __restrict__ offdeg, const unsigned short* __restrict__ csr,
    unsigned short* __restrict__ dout_u16)
{
    int r = (blockIdx.x * blockDim.x + threadIdx.x) >> 6;
    if (r >= NTOT) return;
    const int lane = threadIdx.x & 63;
    const unsigned short* Tg;
    unsigned short* outp;
    if (r < N_ITEM) { Tg = T_user; outp = dout_u16 + (size_t)(N_USER + r) * 256; }
    else            { Tg = T_item; outp = dout_u16 + (size_t)(r - N_ITEM) * 256; }

    const uint2 od = offdeg[r];
    const int o0 = (int)od.x;
    const int deg = (int)od.y;
    const int o1 = o0 + deg;
    const int co = lane * 2;
    float ax = 0.f, ay = 0.f;
    int i = o0;

    // main: 16 edges per chunk, all gathers independent, srcs in SGPRs
    for (; i + 15 < o1; i += 16) {
        int cv = csr[i + (lane & 15)];
        unsigned int w[16];
#pragma unroll
        for (int p = 0; p < 16; ++p) {
            int s = __builtin_amdgcn_readlane(cv, p);
            w[p] = *reinterpret_cast<const unsigned int*>(Tg + (size_t)s * 128 + co);
        }
#pragma unroll
        for (int p = 0; p < 16; ++p) {
            ax += bf2f((unsigned short)w[p]);
            ay += bf2f((unsigned short)(w[p] >> 16));
        }
    }

    // tail: one chunk load (csr padded), 8/4/2/1 parallel levels
    int rem = o1 - i;
    if (rem > 0) {
        int cv = csr[i + (lane & 15)];
        int bl = 0;
        if (rem >= 8) {
            unsigned int w[8];
#pragma unroll
            for (int p = 0; p < 8; ++p) {
                int s = __builtin_amdgcn_readlane(cv, p);
                w[p] = *reinterpret_cast<const unsigned int*>(Tg + (size_t)s * 128 + co);
            }
#pragma unroll
            for (int p = 0; p < 8; ++p) {
                ax += bf2f((unsigned short)w[p]);
                ay += bf2f((unsigned short)(w[p] >> 16));
            }
            bl = 8; rem -= 8;
        }
        if (rem >= 4) {
            unsigned int w[4];
#pragma unroll
            for (int p = 0; p < 4; ++p) {
                int s = __builtin_amdgcn_readlane(cv, bl + p);
                w[p] = *reinterpret_cast<const unsigned int*>(Tg + (size_t)s * 128 + co);
            }
#pragma unroll
            for (int p = 0; p < 4; ++p) {
                ax += bf2f((unsigned short)w[p]);
                ay += bf2f((unsigned short)(w[p] >> 16));
            }
            bl += 4; rem -= 4;
        }
        if (rem >= 2) {
            int s0 = __builtin_amdgcn_readlane(cv, bl);
            int s1 = __builtin_amdgcn_readlane(cv, bl + 1);
            unsigned int w0 = *reinterpret_cast<const unsigned int*>(Tg + (size_t)s0 * 128 + co);
            unsigned int w1 = *reinterpret_cast<const unsigned int*>(Tg + (size_t)s1 * 128 + co);
            ax += bf2f((unsigned short)w0) + bf2f((unsigned short)w1);
            ay += bf2f((unsigned short)(w0 >> 16)) + bf2f((unsigned short)(w1 >> 16));
            bl += 2; rem -= 2;
        }
        if (rem >= 1) {
            int s = __builtin_amdgcn_readlane(cv, bl);
            unsigned int w = *reinterpret_cast<const unsigned int*>(Tg + (size_t)s * 128 + co);
            ax += bf2f((unsigned short)w);
            ay += bf2f((unsigned short)(w >> 16));
        }
    }

    float sc = (deg > 0) ? 1.0f / (float)deg : 0.0f;
    unsigned int outw = (unsigned int)f2bf(ax * sc) | ((unsigned int)f2bf(ay * sc) << 16);
    *reinterpret_cast<unsigned int*>(outp + co) = outw;
}

// ---------------------------------------------------------------------------
// MFMA finish (round-6 structure), head from d_out (stride 256, in-place
// row-aliased: bf16[r][256] == fp32[r][128] bytes; wave stores depend on all
// its loads; waves own disjoint rows), tail from compact self table Ts.
// ---------------------------------------------------------------------------
#define NB_FIN 782   // ceil(50000/64)

__global__ __launch_bounds__(256) void finish2c_kernel(
    unsigned short* dout_u16,
    const unsigned short* __restrict__ T_user, const unsigned short* __restrict__ T_item,
    const unsigned short* __restrict__ WfragUI, const unsigned short* __restrict__ WfragIU,
    const float* __restrict__ b_ui, const float* __restrict__ b_iu)
{
    const int b = blockIdx.x;
    const unsigned short *headBase, *Ts, *Wfrag;
    const float* bias;
    float* outp;
    int rowBase;
    if (b < NB_FIN) {
        headBase = dout_u16 + (size_t)N_USER * 256;
        Ts = T_item; Wfrag = WfragUI; bias = b_ui;
        outp = reinterpret_cast<float*>(dout_u16) + (size_t)N_USER * 128;
        rowBase = b * 64;
    } else {
        headBase = dout_u16;
        Ts = T_user; Wfrag = WfragIU; bias = b_iu;
        outp = reinterpret_cast<float*>(dout_u16);
        rowBase = (b - NB_FIN) * 64;
    }

    const int tid  = threadIdx.x;
    const int wave = tid >> 6;
    const int lane = tid & 63;
    const int kg   = lane >> 4;
    rowBase += wave * 16;

    int arow = rowBase + (lane & 15);
    int arow_c = (arow < 50000) ? arow : 49999;
    const unsigned short* head_ptr = headBase + (size_t)arow_c * 256 + kg * 8;
    const unsigned short* tail_ptr = Ts + (size_t)arow_c * 128 + kg * 8;

    f32x4 acc[8];
#pragma unroll
    for (int c = 0; c < 8; ++c) acc[c] = (f32x4){0.f, 0.f, 0.f, 0.f};

#pragma unroll
    for (int ks = 0; ks < 8; ++ks) {
        bf16x8 a;
        if (ks < 4) a = *reinterpret_cast<const bf16x8*>(head_ptr + ks * 32);       // agg (Wl)
        else        a = *reinterpret_cast<const bf16x8*>(tail_ptr + (ks - 4) * 32); // self (Wr)
        const unsigned short* bptr = Wfrag + ((size_t)(ks * 8) * 64 + lane) * 8;
#pragma unroll
        for (int c = 0; c < 8; ++c) {
            bf16x8 bb = *reinterpret_cast<const bf16x8*>(bptr + (size_t)c * 512);
            acc[c] = __builtin_amdgcn_mfma_f32_16x16x32_bf16(a, bb, acc[c], 0, 0, 0);
        }
    }

    const int orow0 = rowBase + kg * 4;
    const int ocol  = lane & 15;
#pragma unroll
    for (int c = 0; c < 8; ++c) {
        float bv = bias[c * 16 + ocol];
#pragma unroll
        for (int r = 0; r < 4; ++r) {
            int row = orow0 + r;
            if (row < 50000) outp[(size_t)row * 128 + c * 16 + ocol] = acc[c][r] + bv;
        }
    }
}

// ---------------------------------------------------------------------------
extern "C" void kernel_launch(void* const* d_in, const int* in_sizes, int n_in,
                              void* d_out, int out_size, void* d_ws, size_t ws_size,
                              hipStream_t stream) {
    const int*   user_ids = (const int*)d_in[0];
    const float* item_x   = (const float*)d_in[1];
    const int*   edge_ui  = (const int*)d_in[2];
    const int*   edge_iu  = (const int*)d_in[3];
    const float* user_emb = (const float*)d_in[4];
    const float* W_l_ui   = (const float*)d_in[5];
    const float* W_r_ui   = (const float*)d_in[6];
    const float* b_ui     = (const float*)d_in[7];
    const float* W_l_iu   = (const float*)d_in[8];
    const float* W_r_iu   = (const float*)d_in[9];
    const float* b_iu     = (const float*)d_in[10];

    unsigned short* dout_u16 = (unsigned short*)d_out;

    // Workspace (16B-aligned blocks first)
    unsigned short* WfragUI = (unsigned short*)d_ws;            // 32768 u16
    unsigned short* WfragIU = WfragUI + 32768;                  // 32768 u16
    unsigned short* T_user  = WfragIU + 32768;                  // 12.8MB
    unsigned short* T_item  = T_user + (size_t)N_USER * 128;    // 12.8MB
    unsigned int*   records = (unsigned int*)(T_item + (size_t)N_ITEM * 128);  // NBKT*SLOT (8.0MB)
    unsigned short* csr     = (unsigned short*)(records + (size_t)NBKT * SLOT); // NBKT*SLOT+16 (4.0MB)
    uint2* offdeg = (uint2*)(csr + (size_t)NBKT * SLOT + 16);   // NTOT (800KB)
    int*   bcur   = (int*)(offdeg + NTOT);                      // NBKT

    hipMemsetAsync(bcur, 0, NBKT * sizeof(int), stream);

    scatterpack_kernel<<<SCAT_BLOCKS + PACK_BLOCKS + PACKW_BLOCKS, 1024, 0, stream>>>(
        user_emb, user_ids, item_x, edge_ui, edge_iu,
        W_l_ui, W_r_ui, W_l_iu, W_r_iu,
        T_user, T_item, WfragUI, WfragIU, bcur, records);
    csr_build_kernel<<<NBKT, 1024, 0, stream>>>(records, bcur, csr, offdeg);
    agg2c_kernel<<<(NTOT * 64) / 256, 256, 0, stream>>>(T_user, T_item, offdeg, csr, dout_u16);
    finish2c_kernel<<<2 * NB_FIN, 256, 0, stream>>>(
        dout_u16, T_user, T_item, WfragUI, WfragIU, b_ui, b_iu);
}